// Round 6
// baseline (88.425 us; speedup 1.0000x reference)
//
#include <hip/hip_runtime.h>
#include <math.h>

#define D_DIM 128
#define A_DIM 128
#define SPLIT 4           // sub-blocks per segment
#define NTHREADS 256      // 4 waves per block
#define TROWS 64          // rows per tile (4 waves x 16)
#define PSTRIDE 132       // floats per partial record: o[128], m, denom, pad

typedef _Float16 f16x8 __attribute__((ext_vector_type(8)));
typedef __attribute__((ext_vector_type(4))) float f32x4;

__device__ __forceinline__ float fast_tanh(float v) {
    float e = __expf(2.0f * v);
    return 1.0f - 2.0f * __builtin_amdgcn_rcpf(e + 1.0f);
}

__device__ __forceinline__ int lower_bound_i32(const int* __restrict__ arr, int n, int val) {
    int lo = 0, hi = n;
    while (lo < hi) {
        int mid = (lo + hi) >> 1;
        if (arr[mid] < val) lo = mid + 1; else hi = mid;
    }
    return lo;
}

// K0: parallel segment bounds (bidx is sorted)
extern "C" __global__ void __launch_bounds__(256)
seg_bounds_kernel(const int* __restrict__ bidx, int N, int B,
                  int* __restrict__ seg_start)
{
    const int i = blockIdx.x * 256 + threadIdx.x;
    if (i <= B) seg_start[i] = lower_bound_i32(bidx, N, i);
}

// K1: per-(segment, quarter) partial with online softmax.
// scores via fp16 2-term-split MFMA (x = ah+al, W1 fp16); b2 cancels.
// x read from HBM exactly once. 4-wave blocks so 3-4 independent blocks/CU
// overlap loads with compute (R4's 8-wave 1-block/CU serialized the pipes).
extern "C" __global__ void __launch_bounds__(NTHREADS)
fused_partial_kernel(const float* __restrict__ x,
                     const int* __restrict__ seg_start,
                     const float* __restrict__ W1,
                     const float* __restrict__ b1,
                     const float* __restrict__ W2,
                     float* __restrict__ part,
                     int N)
{
    __shared__ _Float16 w1s[A_DIM * D_DIM];   // 32 KB, [col][k] XOR-swizzled
    __shared__ float sB1[A_DIM];
    __shared__ float sW2[A_DIM];
    __shared__ float s_lds[TROWS];
    __shared__ float o_red[16 * 32];          // 2 KB epilogue reduce

    const int tid = threadIdx.x;
    const int b   = blockIdx.x >> 2;          // segment
    const int q   = blockIdx.x & (SPLIT - 1); // quarter

    if (tid < A_DIM) { sB1[tid] = b1[tid]; sW2[tid] = W2[tid]; }

    // stage W1: read coalesced [k][c], write transposed+swizzled fp16
    for (int item = tid; item < A_DIM * 16; item += NTHREADS) {
        const int c = item & (A_DIM - 1);
        const int chunk = item >> 7;          // 16B chunk along k (0..15)
        f16x8 vh;
        #pragma unroll
        for (int j = 0; j < 8; ++j)
            vh[j] = (_Float16)W1[(chunk * 8 + j) * A_DIM + c];
        const int addr = c * 256 + ((chunk ^ (c & 15)) << 4);
        *reinterpret_cast<f16x8*>(reinterpret_cast<char*>(w1s) + addr) = vh;
    }
    __syncthreads();

    const int lo  = seg_start[b];
    const int len = seg_start[b + 1] - lo;
    const int nt  = (len + TROWS - 1) >> 6;   // 64-row tiles in segment

    const int lane = tid & 63;
    const int wv   = tid >> 6;          // wave -> local rows wv*16..wv*16+15
    const int lc   = lane & 15;
    const int lg   = lane >> 4;         // 0..3 ; k-group

    float m = -INFINITY;
    float denom = 0.0f;
    float o_part[32];
    #pragma unroll
    for (int v = 0; v < 32; ++v) o_part[v] = 0.0f;

    float4 buf[8];
    if (q < nt) {   // prologue: load this block's first tile
        const int gi = min(lo + q * TROWS + wv * 16 + lc, N - 1);
        const float4* xr = reinterpret_cast<const float4*>(x + (size_t)gi * D_DIM);
        #pragma unroll
        for (int ks = 0; ks < 4; ++ks) {
            buf[2*ks]   = xr[ks*8 + lg*2];
            buf[2*ks+1] = xr[ks*8 + lg*2 + 1];
        }
    }

    for (int tile = q; tile < nt; tile += SPLIT) {
        // split buf -> fp16 hi/lo fragments (k = ks*32 + lg*8 + j)
        f16x8 ah[4], al[4];
        #pragma unroll
        for (int ks = 0; ks < 4; ++ks) {
            float vv[8] = {buf[2*ks].x, buf[2*ks].y, buf[2*ks].z, buf[2*ks].w,
                           buf[2*ks+1].x, buf[2*ks+1].y, buf[2*ks+1].z, buf[2*ks+1].w};
            #pragma unroll
            for (int j = 0; j < 8; ++j) {
                float xv = vv[j];
                _Float16 h = (_Float16)xv;
                ah[ks][j] = h;
                al[ks][j] = (_Float16)(xv - (float)h);
            }
        }

        // prefetch next tile (strided by SPLIT) while we compute
        const int next = tile + SPLIT;
        if (next < nt) {
            const int gi = min(lo + next * TROWS + wv * 16 + lc, N - 1);
            const float4* xr = reinterpret_cast<const float4*>(x + (size_t)gi * D_DIM);
            #pragma unroll
            for (int ks = 0; ks < 4; ++ks) {
                buf[2*ks]   = xr[ks*8 + lg*2];
                buf[2*ks+1] = xr[ks*8 + lg*2 + 1];
            }
        }

        // ---- scores via MFMA ----
        float part0 = 0.f, part1 = 0.f, part2 = 0.f, part3 = 0.f;
        #pragma unroll
        for (int t = 0; t < 8; ++t) {
            f32x4 acc = {0.f, 0.f, 0.f, 0.f};
            const int c = t * 16 + lc;
            const char* base = reinterpret_cast<const char*>(w1s) + c * 256;
            #pragma unroll
            for (int ks = 0; ks < 4; ++ks) {
                const int chunk = ks * 4 + lg;
                f16x8 bh = *reinterpret_cast<const f16x8*>(
                    base + ((chunk ^ (c & 15)) << 4));
                acc = __builtin_amdgcn_mfma_f32_16x16x32_f16(ah[ks], bh, acc, 0, 0, 0);
                acc = __builtin_amdgcn_mfma_f32_16x16x32_f16(al[ks], bh, acc, 0, 0, 0);
            }
            const float b1v = sB1[c], w2v = sW2[c];
            part0 += fast_tanh(acc[0] + b1v) * w2v;
            part1 += fast_tanh(acc[1] + b1v) * w2v;
            part2 += fast_tanh(acc[2] + b1v) * w2v;
            part3 += fast_tanh(acc[3] + b1v) * w2v;
        }
        #pragma unroll
        for (int mk = 8; mk >= 1; mk >>= 1) {
            part0 += __shfl_xor(part0, mk);
            part1 += __shfl_xor(part1, mk);
            part2 += __shfl_xor(part2, mk);
            part3 += __shfl_xor(part3, mk);
        }
        if (lc == 0) {
            const int rb = wv * 16 + lg * 4;        // local row in tile
            const int grow = tile * TROWS + rb;     // row within segment
            s_lds[rb + 0] = (grow + 0 < len) ? part0 : -INFINITY;
            s_lds[rb + 1] = (grow + 1 < len) ? part1 : -INFINITY;
            s_lds[rb + 2] = (grow + 2 < len) ? part2 : -INFINITY;
            s_lds[rb + 3] = (grow + 3 < len) ? part3 : -INFINITY;
        }
        __syncthreads();

        // ---- online softmax update (all waves redundantly, identical) ----
        const float a0 = s_lds[lane];               // 64 rows
        float pm = a0;
        #pragma unroll
        for (int mk = 32; mk >= 1; mk >>= 1) pm = fmaxf(pm, __shfl_xor(pm, mk));
        const float mn = fmaxf(m, pm);
        const float f  = __expf(m - mn);
        float ds = __expf(a0 - mn);
        #pragma unroll
        for (int mk = 32; mk >= 1; mk >>= 1) ds += __shfl_xor(ds, mk);
        denom = denom * f + ds;
        m = mn;

        // ---- accumulate weighted x from in-register fragments ----
        const float w = __expf(s_lds[wv * 16 + lc] - mn);   // this thread's row
        #pragma unroll
        for (int ks = 0; ks < 4; ++ks) {
            #pragma unroll
            for (int j = 0; j < 8; ++j) {
                const int v = ks * 8 + j;
                o_part[v] = fmaf(o_part[v], f,
                                 w * ((float)ah[ks][j] + (float)al[ks][j]));
            }
        }
        __syncthreads();   // protect s_lds before next tile
    }

    // ---- epilogue: reduce over 16 lc-lanes, then over 4 waves ----
    #pragma unroll
    for (int v = 0; v < 32; ++v) {
        #pragma unroll
        for (int mk = 8; mk >= 1; mk >>= 1)
            o_part[v] += __shfl_xor(o_part[v], mk);
    }
    if (lc == 0) {
        #pragma unroll
        for (int v = 0; v < 32; ++v)
            o_red[(wv * 4 + lg) * 32 + v] = o_part[v];
    }
    __syncthreads();

    float* pb = part + (size_t)blockIdx.x * PSTRIDE;
    if (tid < 128) {
        const int lg2 = tid >> 5, v = tid & 31;
        float s = 0.0f;
        #pragma unroll
        for (int w2 = 0; w2 < 4; ++w2) s += o_red[(w2 * 4 + lg2) * 32 + v];
        const int d = (v >> 3) * 32 + lg2 * 8 + (v & 7);
        pb[d] = s;
    }
    if (tid == 0) { pb[128] = m; pb[129] = denom; }
}

// K2: merge SPLIT partials per segment (flash-style rescale), normalize.
extern "C" __global__ void __launch_bounds__(128)
combine_kernel(const float* __restrict__ part, float* __restrict__ out)
{
    const int b = blockIdx.x, d = threadIdx.x;
    const float* pb = part + (size_t)b * SPLIT * PSTRIDE;

    float mq[SPLIT];
    float mstar = -INFINITY;
    #pragma unroll
    for (int q = 0; q < SPLIT; ++q) {
        mq[q] = pb[q * PSTRIDE + 128];
        mstar = fmaxf(mstar, mq[q]);
    }
    if (mstar == -INFINITY) {          // empty segment
        out[b * D_DIM + d] = 0.0f;
        return;
    }
    float den = 0.0f, val = 0.0f;
    #pragma unroll
    for (int q = 0; q < SPLIT; ++q) {
        const float e = __expf(mq[q] - mstar);   // exp(-inf)=0 for empty quarter
        den = fmaf(pb[q * PSTRIDE + 129], e, den);
        val = fmaf(pb[q * PSTRIDE + d],   e, val);
    }
    out[b * D_DIM + d] = val / den;
}

extern "C" void kernel_launch(void* const* d_in, const int* in_sizes, int n_in,
                              void* d_out, int out_size, void* d_ws, size_t ws_size,
                              hipStream_t stream)
{
    const float* x    = (const float*)d_in[0];
    const int*   bidx = (const int*)d_in[1];
    const float* W1   = (const float*)d_in[2];
    const float* b1   = (const float*)d_in[3];
    const float* W2   = (const float*)d_in[4];
    // d_in[5] = b2: cancels in softmax, unused

    const int N = in_sizes[1];
    const int B = out_size / D_DIM;

    char* ws = (char*)d_ws;
    int*   seg_start = (int*)ws;                       // B+1 ints
    float* part      = (float*)(ws + 4096);            // B*SPLIT*PSTRIDE floats

    seg_bounds_kernel<<<(B + 256) / 256, 256, 0, stream>>>(bidx, N, B, seg_start);
    fused_partial_kernel<<<B * SPLIT, NTHREADS, 0, stream>>>(
        x, seg_start, W1, b1, W2, part, N);
    combine_kernel<<<B, 128, 0, stream>>>(part, (float*)d_out);
}